// Round 3
// 383.273 us; speedup vs baseline: 1.0421x; 1.0421x over previous
//
#include <hip/hip_runtime.h>
#include <stdint.h>

typedef unsigned short u16;

#define TN    84768      // B*T*N = 8*12*883
#define NNODE 883
#define DD    128
#define EE    7000
#define FFDIM 2048

typedef short bf16x8 __attribute__((ext_vector_type(8)));
typedef float f32x4  __attribute__((ext_vector_type(4)));
typedef __attribute__((address_space(3))) u16 lds_u16;
typedef const __attribute__((address_space(1))) u16 glb_u16;

__device__ __forceinline__ float bf2f(u16 u) {
    unsigned int x = ((unsigned int)u) << 16;
    return __uint_as_float(x);
}
__device__ __forceinline__ u16 f2bf(float f) {
    unsigned int x = __float_as_uint(f);
    x += 0x7FFFu + ((x >> 16) & 1u);   // round-to-nearest-even
    return (u16)(x >> 16);
}
// sanitize: any Inf/NaN bit pattern -> 0
__device__ __forceinline__ u16 cleanu(u16 u) {
    return (((u >> 7) & 0xFF) == 0xFF) ? (u16)0 : u;
}
__device__ __forceinline__ u16 cleanf(float f) {
    unsigned b = __float_as_uint(f);
    if (((b >> 23) & 0xFF) == 0xFF) return 0;
    return cleanu(f2bf(f));
}

// -------- dtype detect: bf16-packed vs fp32 --------
__global__ __launch_bounds__(256) void k_detect(const unsigned* __restrict__ x,
                                                int* __restrict__ flag) {
    __shared__ int cnt;
    if (threadIdx.x == 0) cnt = 0;
    __syncthreads();
    unsigned w = x[threadIdx.x];
    unsigned e = (w >> 7) & 0xFF;
    int ok = (e >= 96 && e <= 144) || ((w & 0xFFFFu) == 0);
    atomicAdd(&cnt, ok);
    __syncthreads();
    if (threadIdx.x == 0) flag[0] = (cnt < 200) ? 1 : 0;   // 1 = fp32
}

// -------- fused prep: all weight transposes + param sanitize --------
__global__ __launch_bounds__(256) void k_prep(const void* Wl, const void* Wr,
                                              const void* W1, const void* W2,
                                              const void* bl, const void* br,
                                              const void* att, const void* bgat,
                                              const void* b1, const void* b2,
                                              const void* g1, const void* be1,
                                              const void* g2, const void* be2,
                                              u16* __restrict__ wlrT,
                                              u16* __restrict__ w1T,
                                              u16* __restrict__ w2T,
                                              u16* __restrict__ canon,
                                              const int* __restrict__ flag) {
    int f32 = *flag;
    int i = blockIdx.x * 256 + threadIdx.x;
    if (i < 16384) {
        int r = i >> 7, c = i & 127;
        u16 v = f32 ? cleanf(((const float*)Wl)[i]) : cleanu(((const u16*)Wl)[i]);
        wlrT[c * 128 + r] = v;
    } else if (i < 32768) {
        int idx = i - 16384;
        int r = idx >> 7, c = idx & 127;
        u16 v = f32 ? cleanf(((const float*)Wr)[idx]) : cleanu(((const u16*)Wr)[idx]);
        wlrT[16384 + c * 128 + r] = v;
    } else if (i < 294912) {
        int idx = i - 32768;
        int r = idx >> 11, c = idx & 2047;    // [128][2048]
        u16 v = f32 ? cleanf(((const float*)W1)[idx]) : cleanu(((const u16*)W1)[idx]);
        w1T[c * 128 + r] = v;
    } else if (i < 557056) {
        int idx = i - 294912;
        int r = idx >> 7, c = idx & 127;      // [2048][128]
        u16 v = f32 ? cleanf(((const float*)W2)[idx]) : cleanu(((const u16*)W2)[idx]);
        w2T[c * 2048 + r] = v;
    } else if (i < 560256) {
        int p = i - 557056;
        const void* src; int off;
        if      (p < 128)  { src = bl;   off = 0; }
        else if (p < 256)  { src = br;   off = 128; }
        else if (p < 384)  { src = att;  off = 256; }
        else if (p < 512)  { src = bgat; off = 384; }
        else if (p < 2560) { src = b1;   off = 512; }
        else if (p < 2688) { src = b2;   off = 2560; }
        else if (p < 2816) { src = g1;   off = 2688; }
        else if (p < 2944) { src = be1;  off = 2816; }
        else if (p < 3072) { src = g2;   off = 2944; }
        else               { src = be2;  off = 3072; }
        int j = p - off;
        canon[p] = f32 ? cleanf(((const float*)src)[j]) : cleanu(((const u16*)src)[j]);
    }
}

// -------- CSR of the shared 7000-edge graph (dst-indexed); int32/int64 auto --------
__global__ __launch_bounds__(1024) void k_csr(const int* __restrict__ ew,
                                              int* __restrict__ row_off,
                                              int* __restrict__ col) {
    __shared__ int cnt[NNODE];
    __shared__ int offs[NNODE + 1];
    __shared__ int cur[NNODE];
    __shared__ int flag;
    int tid = threadIdx.x;
    if (tid == 0) flag = 0;
    for (int i = tid; i < NNODE; i += 1024) cnt[i] = 0;
    __syncthreads();
    int f = 0;
    for (int j = tid; j < EE; j += 1024) f |= ew[2 * j + 1];
    if (f) atomicOr(&flag, 1);
    __syncthreads();
    bool is32 = (flag != 0);
    for (int e = tid; e < EE; e += 1024) {
        int dst = is32 ? ew[EE + e] : ew[2 * EE + 2 * e];
        if ((unsigned)dst < NNODE) atomicAdd(&cnt[dst], 1);
    }
    __syncthreads();
    if (tid == 0) {
        int run = 0;
        for (int i = 0; i < NNODE; ++i) { offs[i] = run; run += cnt[i]; }
        offs[NNODE] = run;
    }
    __syncthreads();
    for (int i = tid; i < NNODE; i += 1024) cur[i] = offs[i];
    __syncthreads();
    for (int e = tid; e < EE; e += 1024) {
        int src = is32 ? ew[e] : ew[2 * e];
        int dst = is32 ? ew[EE + e] : ew[2 * EE + 2 * e];
        if ((unsigned)dst < NNODE && (unsigned)src < NNODE) {
            int p = atomicAdd(&cur[dst], 1);
            if (p < EE) col[p] = src;
        }
    }
    __syncthreads();
    for (int i = tid; i <= NNODE; i += 1024) row_off[i] = offs[i];
}

// -------- x_l / x_r: [TN,128] @ [128,256] via MFMA --------
__global__ __launch_bounds__(256) void k_linlr(const void* __restrict__ xraw,
                                               const u16* __restrict__ wlrT,  // [256][128]
                                               const u16* __restrict__ canon,
                                               u16* __restrict__ xl, u16* __restrict__ xr,
                                               const int* __restrict__ flag) {
    __shared__ __align__(16) u16 a_tile[64 * 136];
    int f32 = *flag;
    int tid = threadIdx.x;
    int m0 = blockIdx.x * 64;
    for (int it = 0; it < 4; ++it) {
        int idx = it * 256 + tid;
        int row = idx >> 4, cc = idx & 15;
        int gm = m0 + row;
        u16 tmp[8];
#pragma unroll
        for (int j = 0; j < 8; ++j) tmp[j] = 0;
        if (gm < TN) {
            size_t base = (size_t)gm * DD + cc * 8;
            if (f32) {
                float4 v0 = *(const float4*)((const float*)xraw + base);
                float4 v1 = *(const float4*)((const float*)xraw + base + 4);
                tmp[0] = cleanf(v0.x); tmp[1] = cleanf(v0.y);
                tmp[2] = cleanf(v0.z); tmp[3] = cleanf(v0.w);
                tmp[4] = cleanf(v1.x); tmp[5] = cleanf(v1.y);
                tmp[6] = cleanf(v1.z); tmp[7] = cleanf(v1.w);
            } else {
                uint4 v = *(const uint4*)((const u16*)xraw + base);
                unsigned wv[4] = {v.x, v.y, v.z, v.w};
#pragma unroll
                for (int j = 0; j < 8; ++j)
                    tmp[j] = cleanu((u16)((wv[j >> 1] >> ((j & 1) * 16)) & 0xFFFFu));
            }
        }
        uint4 o;
        o.x = (unsigned)tmp[0] | ((unsigned)tmp[1] << 16);
        o.y = (unsigned)tmp[2] | ((unsigned)tmp[3] << 16);
        o.z = (unsigned)tmp[4] | ((unsigned)tmp[5] << 16);
        o.w = (unsigned)tmp[6] | ((unsigned)tmp[7] << 16);
        *(uint4*)(a_tile + row * 136 + cc * 8) = o;
    }
    __syncthreads();
    int wave = tid >> 6, lane = tid & 63, n16 = lane & 15, q = lane >> 4;
    f32x4 acc[16];
#pragma unroll
    for (int t = 0; t < 16; ++t) acc[t] = (f32x4){0, 0, 0, 0};
    const u16* arow = a_tile + (16 * wave + n16) * 136;
#pragma unroll
    for (int ks = 0; ks < 4; ++ks) {
        bf16x8 a = *(const bf16x8*)(arow + ks * 32 + q * 8);
#pragma unroll
        for (int t = 0; t < 16; ++t) {
            bf16x8 b = *(const bf16x8*)(wlrT + ((size_t)(t * 16 + n16)) * DD + ks * 32 + q * 8);
            acc[t] = __builtin_amdgcn_mfma_f32_16x16x32_bf16(a, b, acc[t], 0, 0, 0);
        }
    }
#pragma unroll
    for (int t = 0; t < 16; ++t) {
        int cc = (t & 7) * 16 + n16;
        float bias = bf2f(canon[(t < 8 ? 0 : 128) + cc]);
        u16* dst = (t < 8 ? xl : xr);
#pragma unroll
        for (int reg = 0; reg < 4; ++reg) {
            int mrow = m0 + 16 * wave + 4 * q + reg;
            if (mrow < TN) dst[(size_t)mrow * DD + cc] = f2bf(acc[t][reg] + bias);
        }
    }
}

// -------- 16-lane segment sum --------
__device__ __forceinline__ float segsum16(float p) {
    p += __shfl_xor(p, 1, 16);
    p += __shfl_xor(p, 2, 16);
    p += __shfl_xor(p, 4, 16);
    p += __shfl_xor(p, 8, 16);
    return p;
}

// -------- GATv2: 1 wave/node, 2 packed channels/lane, no-max softmax --------
// v2: col[] register-cached (1 load/lane + shfl broadcast), xl-row loads
// software-pipelined 2 deep (A/B rotation, static regs) to hide L2 latency.
__global__ __launch_bounds__(256) void k_gat(const void* __restrict__ xraw,
                                             const u16* __restrict__ xl,
                                             const u16* xr,
                                             const u16* __restrict__ canon,
                                             const int* __restrict__ row_off,
                                             const int* __restrict__ col,
                                             u16* h1,
                                             const int* __restrict__ flag) {
    int f32 = *flag;
    int tid = threadIdx.x;
    int wave = tid >> 6, lane = tid & 63;
    int g = blockIdx.x * 4 + wave;             // TN % 4 == 0
    int bt = g / NNODE;
    int i = g - bt * NNODE;
    size_t gbase = (size_t)g * DD;
    const u16* xlrow0 = xl + (size_t)bt * NNODE * DD;
    int c2 = lane * 2;
    unsigned uxr = *(const unsigned*)(xr + gbase + c2);
    float xr0 = __uint_as_float(uxr << 16);
    float xr1 = __uint_as_float(uxr & 0xFFFF0000u);
    unsigned uat = *(const unsigned*)(canon + 256 + c2);
    float at0 = __uint_as_float(uat << 16);
    float at1 = __uint_as_float(uat & 0xFFFF0000u);
    unsigned uxs = *(const unsigned*)(xl + gbase + c2);
    float xs0 = __uint_as_float(uxs << 16);
    float xs1 = __uint_as_float(uxs & 0xFFFF0000u);
    float t0 = xs0 + xr0, t1 = xs1 + xr1;
    t0 = fmaxf(t0, 0.2f * t0); t1 = fmaxf(t1, 0.2f * t1);
    float p = t0 * at0 + t1 * at1;
    p += __shfl_xor(p, 1, 8);
    p += __shfl_xor(p, 2, 8);
    p += __shfl_xor(p, 4, 8);
    p = fminf(fmaxf(p, -30.f), 30.f);
    float w = __expf(p);
    float denom = w;
    float a0 = w * xs0, a1 = w * xs1;
    int r0 = row_off[i], r1 = row_off[i + 1];
    int deg = r1 - r0;
    int myj = (lane < deg) ? col[r0 + lane] : 0;   // deg<=64 fast path cache

    // j is wave-uniform (same edge for all lanes) -> branches are uniform
#define NEXTJ(kk) __builtin_amdgcn_readfirstlane(((kk) < 64) ? __shfl(myj, (kk)) : col[r0 + (kk)])
#define EDGE(uvar, okv) do {                                             \
        float _x0 = __uint_as_float((uvar) << 16);                       \
        float _x1 = __uint_as_float((uvar) & 0xFFFF0000u);               \
        float _u0 = _x0 + xr0, _u1 = _x1 + xr1;                          \
        _u0 = fmaxf(_u0, 0.2f * _u0); _u1 = fmaxf(_u1, 0.2f * _u1);      \
        float _q = _u0 * at0 + _u1 * at1;                                \
        _q += __shfl_xor(_q, 1, 8);                                      \
        _q += __shfl_xor(_q, 2, 8);                                      \
        _q += __shfl_xor(_q, 4, 8);                                      \
        _q = fminf(fmaxf(_q, -30.f), 30.f);                              \
        float _w = (okv) ? __expf(_q) : 0.f;                             \
        denom += _w; a0 += _w * _x0; a1 += _w * _x1;                     \
    } while (0)

    unsigned uA = 0, uB = 0;
    bool okA = false, okB = false;
    if (deg > 0) {
        int j = NEXTJ(0); okA = ((unsigned)j < NNODE);
        uA = *(const unsigned*)(xlrow0 + (size_t)(okA ? j : 0) * DD + c2);
    }
    if (deg > 1) {
        int j = NEXTJ(1); okB = ((unsigned)j < NNODE);
        uB = *(const unsigned*)(xlrow0 + (size_t)(okB ? j : 0) * DD + c2);
    }
    int k = 0;
    while (k + 1 < deg) {
        unsigned u = uA; bool ok = okA;
        if (k + 2 < deg) {
            int j = NEXTJ(k + 2); okA = ((unsigned)j < NNODE);
            uA = *(const unsigned*)(xlrow0 + (size_t)(okA ? j : 0) * DD + c2);
        }
        EDGE(u, ok);
        u = uB; ok = okB;
        if (k + 3 < deg) {
            int j = NEXTJ(k + 3); okB = ((unsigned)j < NNODE);
            uB = *(const unsigned*)(xlrow0 + (size_t)(okB ? j : 0) * DD + c2);
        }
        EDGE(u, ok);
        k += 2;
    }
    if (k < deg) EDGE(uA, okA);
#undef EDGE
#undef NEXTJ

    float inv = 1.f / denom;
    unsigned ubg = *(const unsigned*)(canon + 384 + c2);
    float res0, res1;
    if (f32) {
        float2 rr = *(const float2*)((const float*)xraw + gbase + c2);
        unsigned b0 = __float_as_uint(rr.x), b1 = __float_as_uint(rr.y);
        res0 = (((b0 >> 23) & 0xFF) == 0xFF) ? 0.f : rr.x;
        res1 = (((b1 >> 23) & 0xFF) == 0xFF) ? 0.f : rr.y;
    } else {
        unsigned ux = *(const unsigned*)((const u16*)xraw + gbase + c2);
        res0 = bf2f(cleanu((u16)(ux & 0xFFFFu)));
        res1 = bf2f(cleanu((u16)(ux >> 16)));
    }
    float pre0 = a0 * inv + __uint_as_float(ubg << 16) + res0;
    float pre1 = a1 * inv + __uint_as_float(ubg & 0xFFFF0000u) + res1;
    float sum = pre0 + pre1, sq = pre0 * pre0 + pre1 * pre1;
    for (int off = 32; off; off >>= 1) {
        sum += __shfl_xor(sum, off);
        sq  += __shfl_xor(sq, off);
    }
    float mu = sum * (1.0f / 128.0f);
    float var = fmaxf(sq * (1.0f / 128.0f) - mu * mu, 0.f);
    float rs = rsqrtf(var + 1e-5f);
    unsigned ug = *(const unsigned*)(canon + 2688 + c2);
    unsigned ub = *(const unsigned*)(canon + 2816 + c2);
    float h0 = (pre0 - mu) * rs * __uint_as_float(ug << 16) + __uint_as_float(ub << 16);
    float h1v = (pre1 - mu) * rs * __uint_as_float(ug & 0xFFFF0000u) + __uint_as_float(ub & 0xFFFF0000u);
    unsigned out = (unsigned)f2bf(h0) | ((unsigned)f2bf(h1v) << 16);
    *(unsigned*)(h1 + gbase + c2) = out;
}

// -------- fused FFN + residual + LN2: M=128/block, wave=32 rows --------
// v2: T3/T4 minimum 2-phase pipeline. Weight chunks shrunk 64->32 cols and
// DOUBLE-BUFFERED; next chunk's 4 global_load_lds issued before computing
// the current chunk; raw s_barrier + counted `s_waitcnt vmcnt(4)` (never 0
// in steady state) keeps the DMA in flight across the whole compute phase.
// vmcnt ledger per chunk per wave: 4 stage DMA + 2 bias loads, in-order
// retirement => vmcnt(4) at top of chunk ch drains ch's stage (+older bias)
// and leaves ch+1's 4 loads in flight.
// s_t stride 72->40 u16 (20 dwords, odd*4): GEMM2 A-reads provably
// conflict-free. w2b rows are 64 B now -> 2-bit swizzle (r^(r>>2))&3.
// LDS = 2*8192 + 2*8192 + 10240 = 43008 B -> 3 blocks/CU (unchanged).
__global__ __launch_bounds__(256, 3) void k_ffn(const u16* __restrict__ h1,
                                                const u16* __restrict__ w1T,  // [2048][128]
                                                const u16* __restrict__ w2T,  // [128][2048]
                                                const u16* __restrict__ canon,
                                                void* __restrict__ outraw,
                                                const int* __restrict__ flag) {
    __shared__ __align__(16) u16 w1b[2][32 * 128];   // W1 chunk, double-buffered
    __shared__ __align__(16) u16 w2b[2][128 * 32];   // W2 chunk, double-buffered
    __shared__ __align__(16) u16 s_t[128 * 40];      // s = relu(h@W1+b1), stride 40
    int f32 = *flag;
    int tid = threadIdx.x;
    int wave = tid >> 6, lane = tid & 63, n16 = lane & 15, q = lane >> 4;
    int m0 = blockIdx.x * 128;
    int swz = n16 & 7;                       // w1b read swizzle (rows are 256 B)
    int sz2 = (n16 & 3) ^ (n16 >> 2);        // w2b read swizzle: (row^(row>>2))&3
    // A-fragments of h for this wave's 32 rows (2 sub-tiles), regs all kernel
    bf16x8 af[2][4];
#pragma unroll
    for (int sub = 0; sub < 2; ++sub) {
        int gm = m0 + 32 * wave + 16 * sub + n16;
#pragma unroll
        for (int ks = 0; ks < 4; ++ks) {
            if (gm < TN) {
                uint4 v = *(const uint4*)(h1 + (size_t)gm * DD + ks * 32 + q * 8);
                af[sub][ks] = *(const bf16x8*)&v;
            } else {
                uint4 z = make_uint4(0, 0, 0, 0);
                af[sub][ks] = *(const bf16x8*)&z;
            }
        }
    }
    f32x4 acc2[2][8];
#pragma unroll
    for (int sub = 0; sub < 2; ++sub)
#pragma unroll
        for (int t = 0; t < 8; ++t) acc2[sub][t] = (f32x4){0, 0, 0, 0};
    // staging source pointers (pre-swizzled global addresses; advance per chunk)
    const u16 *p1a, *p1b, *p2a, *p2b;
    {
        int r0 = 8 * wave + (lane >> 4);          // W1 load 0: rows 8w..8w+3
        int cb0 = (lane & 15) ^ (r0 & 7);
        p1a = w1T + (size_t)r0 * 128 + cb0 * 8;
        int r1 = r0 + 4;                          // W1 load 1: rows 8w+4..8w+7
        int cb1 = (lane & 15) ^ (r1 & 7);
        p1b = w1T + (size_t)r1 * 128 + cb1 * 8;
        int s0 = 32 * wave + (lane >> 2);         // W2 load 0: rows 32w..32w+15
        int sc0 = (lane & 3) ^ (((lane >> 2) & 3) ^ (lane >> 4));
        p2a = w2T + (size_t)s0 * 2048 + sc0 * 8;
        int s1 = s0 + 16;                         // W2 load 1: rows 32w+16..32w+31
        int sc1 = (lane & 3) ^ (((lane >> 2) & 3) ^ (lane >> 4));  // same fn of lane
        p2b = w2T + (size_t)s1 * 2048 + sc1 * 8;
    }
#define STAGE(f0v, buf) do {                                                          \
        __builtin_amdgcn_global_load_lds(                                             \
            (const __attribute__((address_space(1))) unsigned*)(p1a + (size_t)(f0v) * 128), \
            (__attribute__((address_space(3))) unsigned*)(lds_u16*)&w1b[buf][(8 * wave) * 128], 16, 0, 0); \
        __builtin_amdgcn_global_load_lds(                                             \
            (const __attribute__((address_space(1))) unsigned*)(p1b + (size_t)(f0v) * 128), \
            (__attribute__((address_space(3))) unsigned*)(lds_u16*)&w1b[buf][(8 * wave + 4) * 128], 16, 0, 0); \
        __builtin_amdgcn_global_load_lds(                                             \
            (const __attribute__((address_space(1))) unsigned*)(p2a + (f0v)),         \
            (__attribute__((address_space(3))) unsigned*)(lds_u16*)&w2b[buf][(32 * wave) * 32], 16, 0, 0); \
        __builtin_amdgcn_global_load_lds(                                             \
            (const __attribute__((address_space(1))) unsigned*)(p2b + (f0v)),         \
            (__attribute__((address_space(3))) unsigned*)(lds_u16*)&w2b[buf][(32 * wave + 16) * 32], 16, 0, 0); \
    } while (0)

    u16* sw0 = s_t + (32 * wave + 4 * q) * 40;        // sub0 write rows
    u16* sw1 = sw0 + 16 * 40;                         // sub1 write rows
    const u16* sr0 = s_t + (32 * wave + n16) * 40;    // sub0 read row
    const u16* sr1 = sr0 + 16 * 40;                   // sub1 read row

    STAGE(0, 0);                                      // prologue: chunk 0 -> buf 0
    for (int ch = 0; ch < 64; ++ch) {
        int cur = ch & 1;
        if (ch + 1 < 64) {
            STAGE((ch + 1) * 32, cur ^ 1);            // issue next chunk first
            asm volatile("s_waitcnt vmcnt(4)" ::: "memory");   // current chunk ready
        } else {
            asm volatile("s_waitcnt vmcnt(0)" ::: "memory");
        }
        __builtin_amdgcn_s_barrier();                 // all waves' stage visible
        int f0 = ch * 32;
        const u16* w1c = &w1b[cur][0];
        const u16* w2c = &w2b[cur][0];
        // GEMM1: s = relu(h @ W1chunk + b1); each b-frag feeds both sub-tiles
#pragma unroll
        for (int t = 0; t < 2; ++t) {
            f32x4 a10 = (f32x4){0, 0, 0, 0};
            f32x4 a11 = (f32x4){0, 0, 0, 0};
#pragma unroll
            for (int ks = 0; ks < 4; ++ks) {
                bf16x8 b = *(const bf16x8*)(w1c + (t * 16 + n16) * 128 + (((ks * 4 + q) ^ swz) * 8));
                a10 = __builtin_amdgcn_mfma_f32_16x16x32_bf16(af[0][ks], b, a10, 0, 0, 0);
                a11 = __builtin_amdgcn_mfma_f32_16x16x32_bf16(af[1][ks], b, a11, 0, 0, 0);
            }
            float bb = bf2f(canon[512 + f0 + t * 16 + n16]);
#pragma unroll
            for (int reg = 0; reg < 4; ++reg) {
                float v0 = a10[reg] + bb;
                float v1 = a11[reg] + bb;
                v0 = v0 > 0.f ? v0 : 0.f;
                v1 = v1 > 0.f ? v1 : 0.f;
                sw0[reg * 40 + t * 16 + n16] = f2bf(v0);
                sw1[reg * 40 + t * 16 + n16] = f2bf(v1);
            }
        }
        asm volatile("" ::: "memory");
        // GEMM2: acc2 += s @ W2chunk (s rows wave-private; per-wave DS order ok)
        bf16x8 a20 = *(const bf16x8*)(sr0 + q * 8);
        bf16x8 a21 = *(const bf16x8*)(sr1 + q * 8);
#pragma unroll
        for (int t = 0; t < 8; ++t) {
            bf16x8 b = *(const bf16x8*)(w2c + (t * 16 + n16) * 32 + ((q ^ sz2) * 8));
            acc2[0][t] = __builtin_amdgcn_mfma_f32_16x16x32_bf16(a20, b, acc2[0][t], 0, 0, 0);
            acc2[1][t] = __builtin_amdgcn_mfma_f32_16x16x32_bf16(a21, b, acc2[1][t], 0, 0, 0);
        }
        __builtin_amdgcn_s_barrier();   // all reads of buf[cur] done before its re-stage
    }
#undef STAGE
    // epilogue: +b2 +residual, LN2 via 16-lane shuffles (row lives in one quad)
    float b2v[8], g2v[8], e2v[8];
#pragma unroll
    for (int t = 0; t < 8; ++t) {
        int col = t * 16 + n16;
        b2v[t] = bf2f(canon[2560 + col]);
        g2v[t] = bf2f(canon[2944 + col]);
        e2v[t] = bf2f(canon[3072 + col]);
    }
#pragma unroll
    for (int sub = 0; sub < 2; ++sub) {
#pragma unroll
        for (int reg = 0; reg < 4; ++reg) {
            int row = 32 * wave + 16 * sub + 4 * q + reg;
            int gm = m0 + row;
            bool ok = gm < TN;
            size_t gb = (size_t)(ok ? gm : 0) * DD;
            float v[8]; float s1 = 0.f, s2 = 0.f;
#pragma unroll
            for (int t = 0; t < 8; ++t) {
                float hres = bf2f(h1[gb + t * 16 + n16]);
                v[t] = acc2[sub][t][reg] + b2v[t] + hres;
                s1 += v[t]; s2 += v[t] * v[t];
            }
            s1 = segsum16(s1);
            s2 = segsum16(s2);
            float mu = s1 * (1.f / 128.f);
            float var = fmaxf(s2 * (1.f / 128.f) - mu * mu, 0.f);
            float rs = rsqrtf(var + 1e-5f);
            if (ok) {
#pragma unroll
                for (int t = 0; t < 8; ++t) {
                    float r = (v[t] - mu) * rs * g2v[t] + e2v[t];
                    if (f32) ((float*)outraw)[gb + t * 16 + n16] = r;
                    else     ((u16*)outraw)[gb + t * 16 + n16] = f2bf(r);
                }
            }
        }
    }
}

extern "C" void kernel_launch(void* const* d_in, const int* in_sizes, int n_in,
                              void* d_out, int out_size, void* d_ws, size_t ws_size,
                              hipStream_t stream) {
    const void* x    = d_in[0];
    const int* eidx  = (const int*)d_in[1];
    const void* Wl   = d_in[2];
    const void* bl   = d_in[3];
    const void* Wr   = d_in[4];
    const void* br   = d_in[5];
    const void* att  = d_in[6];
    const void* bgat = d_in[7];
    const void* W1   = d_in[8];
    const void* b1   = d_in[9];
    const void* W2   = d_in[10];
    const void* b2   = d_in[11];
    const void* g1   = d_in[12];
    const void* be1  = d_in[13];
    const void* g2   = d_in[14];
    const void* be2  = d_in[15];

    // ws layout (bytes): flag@0, rowoff@4096, colw@8192, canon@36864,
    // wlrT@65536, w1T@131072, w2T@655360, xl@1179648, xr/h1@22880256
    char* ws = (char*)d_ws;
    int* flag   = (int*)(ws);
    int* rowoff = (int*)(ws + 4096);
    int* colw   = (int*)(ws + 8192);
    u16* canon  = (u16*)(ws + 36864);
    u16* wlrT   = (u16*)(ws + 65536);
    u16* w1T    = (u16*)(ws + 131072);
    u16* w2T    = (u16*)(ws + 655360);
    u16* xl     = (u16*)(ws + 1179648);
    u16* xr     = (u16*)(ws + 22880256);
    u16* h1     = xr;   // k_gat reads xr[addr] before writing h1[addr]

    k_csr<<<1, 1024, 0, stream>>>(eidx, rowoff, colw);
    k_detect<<<1, 256, 0, stream>>>((const unsigned*)x, flag);
    k_prep<<<2189, 256, 0, stream>>>(Wl, Wr, W1, W2, bl, br, att, bgat, b1, b2,
                                     g1, be1, g2, be2, wlrT, w1T, w2T, canon, flag);
    k_linlr<<<(TN + 63) / 64, 256, 0, stream>>>(x, wlrT, canon, xl, xr, flag);
    k_gat<<<TN / 4, 256, 0, stream>>>(x, xl, xr, canon, rowoff, colw, h1, flag);
    k_ffn<<<(TN + 127) / 128, 256, 0, stream>>>(h1, w1T, w2T, canon, d_out, flag);
}

// Round 6
// 373.075 us; speedup vs baseline: 1.0706x; 1.0273x over previous
//
#include <hip/hip_runtime.h>
#include <stdint.h>

typedef unsigned short u16;

#define TN    84768      // B*T*N = 8*12*883
#define NNODE 883
#define DD    128
#define EE    7000
#define FFDIM 2048

typedef short bf16x8 __attribute__((ext_vector_type(8)));
typedef float f32x4  __attribute__((ext_vector_type(4)));
typedef __attribute__((address_space(3))) u16 lds_u16;
typedef const __attribute__((address_space(1))) u16 glb_u16;

__device__ __forceinline__ float bf2f(u16 u) {
    unsigned int x = ((unsigned int)u) << 16;
    return __uint_as_float(x);
}
__device__ __forceinline__ u16 f2bf(float f) {
    unsigned int x = __float_as_uint(f);
    x += 0x7FFFu + ((x >> 16) & 1u);   // round-to-nearest-even
    return (u16)(x >> 16);
}
// sanitize: any Inf/NaN bit pattern -> 0
__device__ __forceinline__ u16 cleanu(u16 u) {
    return (((u >> 7) & 0xFF) == 0xFF) ? (u16)0 : u;
}
__device__ __forceinline__ u16 cleanf(float f) {
    unsigned b = __float_as_uint(f);
    if (((b >> 23) & 0xFF) == 0xFF) return 0;
    return cleanu(f2bf(f));
}

// -------- dtype detect: bf16-packed vs fp32 --------
__global__ __launch_bounds__(256) void k_detect(const unsigned* __restrict__ x,
                                                int* __restrict__ flag) {
    __shared__ int cnt;
    if (threadIdx.x == 0) cnt = 0;
    __syncthreads();
    unsigned w = x[threadIdx.x];
    unsigned e = (w >> 7) & 0xFF;
    int ok = (e >= 96 && e <= 144) || ((w & 0xFFFFu) == 0);
    atomicAdd(&cnt, ok);
    __syncthreads();
    if (threadIdx.x == 0) flag[0] = (cnt < 200) ? 1 : 0;   // 1 = fp32
}

// -------- fused prep: all weight transposes + param sanitize --------
__global__ __launch_bounds__(256) void k_prep(const void* Wl, const void* Wr,
                                              const void* W1, const void* W2,
                                              const void* bl, const void* br,
                                              const void* att, const void* bgat,
                                              const void* b1, const void* b2,
                                              const void* g1, const void* be1,
                                              const void* g2, const void* be2,
                                              u16* __restrict__ wlrT,
                                              u16* __restrict__ w1T,
                                              u16* __restrict__ w2T,
                                              u16* __restrict__ canon,
                                              const int* __restrict__ flag) {
    int f32 = *flag;
    int i = blockIdx.x * 256 + threadIdx.x;
    if (i < 16384) {
        int r = i >> 7, c = i & 127;
        u16 v = f32 ? cleanf(((const float*)Wl)[i]) : cleanu(((const u16*)Wl)[i]);
        wlrT[c * 128 + r] = v;
    } else if (i < 32768) {
        int idx = i - 16384;
        int r = idx >> 7, c = idx & 127;
        u16 v = f32 ? cleanf(((const float*)Wr)[idx]) : cleanu(((const u16*)Wr)[idx]);
        wlrT[16384 + c * 128 + r] = v;
    } else if (i < 294912) {
        int idx = i - 32768;
        int r = idx >> 11, c = idx & 2047;    // [128][2048]
        u16 v = f32 ? cleanf(((const float*)W1)[idx]) : cleanu(((const u16*)W1)[idx]);
        w1T[c * 128 + r] = v;
    } else if (i < 557056) {
        int idx = i - 294912;
        int r = idx >> 7, c = idx & 127;      // [2048][128]
        u16 v = f32 ? cleanf(((const float*)W2)[idx]) : cleanu(((const u16*)W2)[idx]);
        w2T[c * 2048 + r] = v;
    } else if (i < 560256) {
        int p = i - 557056;
        const void* src; int off;
        if      (p < 128)  { src = bl;   off = 0; }
        else if (p < 256)  { src = br;   off = 128; }
        else if (p < 384)  { src = att;  off = 256; }
        else if (p < 512)  { src = bgat; off = 384; }
        else if (p < 2560) { src = b1;   off = 512; }
        else if (p < 2688) { src = b2;   off = 2560; }
        else if (p < 2816) { src = g1;   off = 2688; }
        else if (p < 2944) { src = be1;  off = 2816; }
        else if (p < 3072) { src = g2;   off = 2944; }
        else               { src = be2;  off = 3072; }
        int j = p - off;
        canon[p] = f32 ? cleanf(((const float*)src)[j]) : cleanu(((const u16*)src)[j]);
    }
}

// -------- CSR of the shared 7000-edge graph (dst-indexed); int32/int64 auto --------
__global__ __launch_bounds__(1024) void k_csr(const int* __restrict__ ew,
                                              int* __restrict__ row_off,
                                              int* __restrict__ col) {
    __shared__ int cnt[NNODE];
    __shared__ int offs[NNODE + 1];
    __shared__ int cur[NNODE];
    __shared__ int flag;
    int tid = threadIdx.x;
    if (tid == 0) flag = 0;
    for (int i = tid; i < NNODE; i += 1024) cnt[i] = 0;
    __syncthreads();
    int f = 0;
    for (int j = tid; j < EE; j += 1024) f |= ew[2 * j + 1];
    if (f) atomicOr(&flag, 1);
    __syncthreads();
    bool is32 = (flag != 0);
    for (int e = tid; e < EE; e += 1024) {
        int dst = is32 ? ew[EE + e] : ew[2 * EE + 2 * e];
        if ((unsigned)dst < NNODE) atomicAdd(&cnt[dst], 1);
    }
    __syncthreads();
    if (tid == 0) {
        int run = 0;
        for (int i = 0; i < NNODE; ++i) { offs[i] = run; run += cnt[i]; }
        offs[NNODE] = run;
    }
    __syncthreads();
    for (int i = tid; i < NNODE; i += 1024) cur[i] = offs[i];
    __syncthreads();
    for (int e = tid; e < EE; e += 1024) {
        int src = is32 ? ew[e] : ew[2 * e];
        int dst = is32 ? ew[EE + e] : ew[2 * EE + 2 * e];
        if ((unsigned)dst < NNODE && (unsigned)src < NNODE) {
            int p = atomicAdd(&cur[dst], 1);
            if (p < EE) col[p] = src;
        }
    }
    __syncthreads();
    for (int i = tid; i <= NNODE; i += 1024) row_off[i] = offs[i];
}

// -------- x_l / x_r: [TN,128] @ [128,256] via MFMA --------
__global__ __launch_bounds__(256) void k_linlr(const void* __restrict__ xraw,
                                               const u16* __restrict__ wlrT,  // [256][128]
                                               const u16* __restrict__ canon,
                                               u16* __restrict__ xl, u16* __restrict__ xr,
                                               const int* __restrict__ flag) {
    __shared__ __align__(16) u16 a_tile[64 * 136];
    int f32 = *flag;
    int tid = threadIdx.x;
    int m0 = blockIdx.x * 64;
    for (int it = 0; it < 4; ++it) {
        int idx = it * 256 + tid;
        int row = idx >> 4, cc = idx & 15;
        int gm = m0 + row;
        u16 tmp[8];
#pragma unroll
        for (int j = 0; j < 8; ++j) tmp[j] = 0;
        if (gm < TN) {
            size_t base = (size_t)gm * DD + cc * 8;
            if (f32) {
                float4 v0 = *(const float4*)((const float*)xraw + base);
                float4 v1 = *(const float4*)((const float*)xraw + base + 4);
                tmp[0] = cleanf(v0.x); tmp[1] = cleanf(v0.y);
                tmp[2] = cleanf(v0.z); tmp[3] = cleanf(v0.w);
                tmp[4] = cleanf(v1.x); tmp[5] = cleanf(v1.y);
                tmp[6] = cleanf(v1.z); tmp[7] = cleanf(v1.w);
            } else {
                uint4 v = *(const uint4*)((const u16*)xraw + base);
                unsigned wv[4] = {v.x, v.y, v.z, v.w};
#pragma unroll
                for (int j = 0; j < 8; ++j)
                    tmp[j] = cleanu((u16)((wv[j >> 1] >> ((j & 1) * 16)) & 0xFFFFu));
            }
        }
        uint4 o;
        o.x = (unsigned)tmp[0] | ((unsigned)tmp[1] << 16);
        o.y = (unsigned)tmp[2] | ((unsigned)tmp[3] << 16);
        o.z = (unsigned)tmp[4] | ((unsigned)tmp[5] << 16);
        o.w = (unsigned)tmp[6] | ((unsigned)tmp[7] << 16);
        *(uint4*)(a_tile + row * 136 + cc * 8) = o;
    }
    __syncthreads();
    int wave = tid >> 6, lane = tid & 63, n16 = lane & 15, q = lane >> 4;
    f32x4 acc[16];
#pragma unroll
    for (int t = 0; t < 16; ++t) acc[t] = (f32x4){0, 0, 0, 0};
    const u16* arow = a_tile + (16 * wave + n16) * 136;
#pragma unroll
    for (int ks = 0; ks < 4; ++ks) {
        bf16x8 a = *(const bf16x8*)(arow + ks * 32 + q * 8);
#pragma unroll
        for (int t = 0; t < 16; ++t) {
            bf16x8 b = *(const bf16x8*)(wlrT + ((size_t)(t * 16 + n16)) * DD + ks * 32 + q * 8);
            acc[t] = __builtin_amdgcn_mfma_f32_16x16x32_bf16(a, b, acc[t], 0, 0, 0);
        }
    }
#pragma unroll
    for (int t = 0; t < 16; ++t) {
        int cc = (t & 7) * 16 + n16;
        float bias = bf2f(canon[(t < 8 ? 0 : 128) + cc]);
        u16* dst = (t < 8 ? xl : xr);
#pragma unroll
        for (int reg = 0; reg < 4; ++reg) {
            int mrow = m0 + 16 * wave + 4 * q + reg;
            if (mrow < TN) dst[(size_t)mrow * DD + cc] = f2bf(acc[t][reg] + bias);
        }
    }
}

// -------- 16-lane segment sum --------
__device__ __forceinline__ float segsum16(float p) {
    p += __shfl_xor(p, 1, 16);
    p += __shfl_xor(p, 2, 16);
    p += __shfl_xor(p, 4, 16);
    p += __shfl_xor(p, 8, 16);
    return p;
}

// -------- GATv2: 1 wave/node, 2 packed channels/lane, no-max softmax --------
// v2 (round-3 proven): col[] register-cached (1 load/lane + shfl broadcast),
// xl-row loads software-pipelined 2 deep (A/B rotation, static regs).
__global__ __launch_bounds__(256) void k_gat(const void* __restrict__ xraw,
                                             const u16* __restrict__ xl,
                                             const u16* xr,
                                             const u16* __restrict__ canon,
                                             const int* __restrict__ row_off,
                                             const int* __restrict__ col,
                                             u16* h1,
                                             const int* __restrict__ flag) {
    int f32 = *flag;
    int tid = threadIdx.x;
    int wave = tid >> 6, lane = tid & 63;
    int g = blockIdx.x * 4 + wave;             // TN % 4 == 0
    int bt = g / NNODE;
    int i = g - bt * NNODE;
    size_t gbase = (size_t)g * DD;
    const u16* xlrow0 = xl + (size_t)bt * NNODE * DD;
    int c2 = lane * 2;
    unsigned uxr = *(const unsigned*)(xr + gbase + c2);
    float xr0 = __uint_as_float(uxr << 16);
    float xr1 = __uint_as_float(uxr & 0xFFFF0000u);
    unsigned uat = *(const unsigned*)(canon + 256 + c2);
    float at0 = __uint_as_float(uat << 16);
    float at1 = __uint_as_float(uat & 0xFFFF0000u);
    unsigned uxs = *(const unsigned*)(xl + gbase + c2);
    float xs0 = __uint_as_float(uxs << 16);
    float xs1 = __uint_as_float(uxs & 0xFFFF0000u);
    float t0 = xs0 + xr0, t1 = xs1 + xr1;
    t0 = fmaxf(t0, 0.2f * t0); t1 = fmaxf(t1, 0.2f * t1);
    float p = t0 * at0 + t1 * at1;
    p += __shfl_xor(p, 1, 8);
    p += __shfl_xor(p, 2, 8);
    p += __shfl_xor(p, 4, 8);
    p = fminf(fmaxf(p, -30.f), 30.f);
    float w = __expf(p);
    float denom = w;
    float a0 = w * xs0, a1 = w * xs1;
    int r0 = row_off[i], r1 = row_off[i + 1];
    int deg = r1 - r0;
    int myj = (lane < deg) ? col[r0 + lane] : 0;   // deg<=64 fast path cache

    // j is wave-uniform (same edge for all lanes) -> branches are uniform
#define NEXTJ(kk) __builtin_amdgcn_readfirstlane(((kk) < 64) ? __shfl(myj, (kk)) : col[r0 + (kk)])
#define EDGE(uvar, okv) do {                                             \
        float _x0 = __uint_as_float((uvar) << 16);                       \
        float _x1 = __uint_as_float((uvar) & 0xFFFF0000u);               \
        float _u0 = _x0 + xr0, _u1 = _x1 + xr1;                          \
        _u0 = fmaxf(_u0, 0.2f * _u0); _u1 = fmaxf(_u1, 0.2f * _u1);      \
        float _q = _u0 * at0 + _u1 * at1;                                \
        _q += __shfl_xor(_q, 1, 8);                                      \
        _q += __shfl_xor(_q, 2, 8);                                      \
        _q += __shfl_xor(_q, 4, 8);                                      \
        _q = fminf(fmaxf(_q, -30.f), 30.f);                              \
        float _w = (okv) ? __expf(_q) : 0.f;                             \
        denom += _w; a0 += _w * _x0; a1 += _w * _x1;                     \
    } while (0)

    unsigned uA = 0, uB = 0;
    bool okA = false, okB = false;
    if (deg > 0) {
        int j = NEXTJ(0); okA = ((unsigned)j < NNODE);
        uA = *(const unsigned*)(xlrow0 + (size_t)(okA ? j : 0) * DD + c2);
    }
    if (deg > 1) {
        int j = NEXTJ(1); okB = ((unsigned)j < NNODE);
        uB = *(const unsigned*)(xlrow0 + (size_t)(okB ? j : 0) * DD + c2);
    }
    int k = 0;
    while (k + 1 < deg) {
        unsigned u = uA; bool ok = okA;
        if (k + 2 < deg) {
            int j = NEXTJ(k + 2); okA = ((unsigned)j < NNODE);
            uA = *(const unsigned*)(xlrow0 + (size_t)(okA ? j : 0) * DD + c2);
        }
        EDGE(u, ok);
        u = uB; ok = okB;
        if (k + 3 < deg) {
            int j = NEXTJ(k + 3); okB = ((unsigned)j < NNODE);
            uB = *(const unsigned*)(xlrow0 + (size_t)(okB ? j : 0) * DD + c2);
        }
        EDGE(u, ok);
        k += 2;
    }
    if (k < deg) EDGE(uA, okA);
#undef EDGE
#undef NEXTJ

    float inv = 1.f / denom;
    unsigned ubg = *(const unsigned*)(canon + 384 + c2);
    float res0, res1;
    if (f32) {
        float2 rr = *(const float2*)((const float*)xraw + gbase + c2);
        unsigned b0 = __float_as_uint(rr.x), b1 = __float_as_uint(rr.y);
        res0 = (((b0 >> 23) & 0xFF) == 0xFF) ? 0.f : rr.x;
        res1 = (((b1 >> 23) & 0xFF) == 0xFF) ? 0.f : rr.y;
    } else {
        unsigned ux = *(const unsigned*)((const u16*)xraw + gbase + c2);
        res0 = bf2f(cleanu((u16)(ux & 0xFFFFu)));
        res1 = bf2f(cleanu((u16)(ux >> 16)));
    }
    float pre0 = a0 * inv + __uint_as_float(ubg << 16) + res0;
    float pre1 = a1 * inv + __uint_as_float(ubg & 0xFFFF0000u) + res1;
    float sum = pre0 + pre1, sq = pre0 * pre0 + pre1 * pre1;
    for (int off = 32; off; off >>= 1) {
        sum += __shfl_xor(sum, off);
        sq  += __shfl_xor(sq, off);
    }
    float mu = sum * (1.0f / 128.0f);
    float var = fmaxf(sq * (1.0f / 128.0f) - mu * mu, 0.f);
    float rs = rsqrtf(var + 1e-5f);
    unsigned ug = *(const unsigned*)(canon + 2688 + c2);
    unsigned ub = *(const unsigned*)(canon + 2816 + c2);
    float h0 = (pre0 - mu) * rs * __uint_as_float(ug << 16) + __uint_as_float(ub << 16);
    float h1v = (pre1 - mu) * rs * __uint_as_float(ug & 0xFFFF0000u) + __uint_as_float(ub & 0xFFFF0000u);
    unsigned out = (unsigned)f2bf(h0) | ((unsigned)f2bf(h1v) << 16);
    *(unsigned*)(h1 + gbase + c2) = out;
}

// -------- fused FFN + residual + LN2: M=128/block, wave=32 rows --------
// Round-0 PROVEN version (128.5us). Async DMA weight staging (swizzled);
// every w1b/w2b b-fragment feeds 2 MFMAs (sub-tiles).
// LDS = 16384 + 16384 + 18432 = 51200 B -> 3 blocks/CU.
__global__ __launch_bounds__(256, 3) void k_ffn(const u16* __restrict__ h1,
                                                const u16* __restrict__ w1T,  // [2048][128]
                                                const u16* __restrict__ w2T,  // [128][2048]
                                                const u16* __restrict__ canon,
                                                void* __restrict__ outraw,
                                                const int* __restrict__ flag) {
    __shared__ __align__(16) u16 w1b[64 * 128];   // chunk of W1, swizzled
    __shared__ __align__(16) u16 w2b[128 * 64];   // chunk of W2, swizzled
    __shared__ __align__(16) u16 s_t[128 * 72];   // s = relu(h@W1+b1), padded
    int f32 = *flag;
    int tid = threadIdx.x;
    int wave = tid >> 6, lane = tid & 63, n16 = lane & 15, q = lane >> 4;
    int m0 = blockIdx.x * 128;
    int swz = n16 & 7;
    // A-fragments of h for this wave's 32 rows (2 sub-tiles), regs all kernel
    bf16x8 af[2][4];
#pragma unroll
    for (int sub = 0; sub < 2; ++sub) {
        int gm = m0 + 32 * wave + 16 * sub + n16;
#pragma unroll
        for (int ks = 0; ks < 4; ++ks) {
            if (gm < TN) {
                uint4 v = *(const uint4*)(h1 + (size_t)gm * DD + ks * 32 + q * 8);
                af[sub][ks] = *(const bf16x8*)&v;
            } else {
                uint4 z = make_uint4(0, 0, 0, 0);
                af[sub][ks] = *(const bf16x8*)&z;
            }
        }
    }
    f32x4 acc2[2][8];
#pragma unroll
    for (int sub = 0; sub < 2; ++sub)
#pragma unroll
        for (int t = 0; t < 8; ++t) acc2[sub][t] = (f32x4){0, 0, 0, 0};
    // DMA staging geometry (whole chunk per block)
    int w1r[4], w1b_log[4];
#pragma unroll
    for (int i = 0; i < 4; ++i) {
        w1r[i] = 16 * wave + 4 * i + (lane >> 4);
        w1b_log[i] = (lane & 15) ^ (w1r[i] & 7);
    }
    int w2r[4], w2b_log[4];
#pragma unroll
    for (int i = 0; i < 4; ++i) {
        w2r[i] = 32 * wave + 8 * i + (lane >> 3);
        w2b_log[i] = (lane & 7) ^ (w2r[i] & 7);
    }
    u16* srow_w0 = s_t + (32 * wave + 4 * q) * 72;        // sub0 write rows
    u16* srow_w1 = s_t + (32 * wave + 16 + 4 * q) * 72;   // sub1 write rows
    const u16* srow_r0 = s_t + (32 * wave + n16) * 72;
    const u16* srow_r1 = s_t + (32 * wave + 16 + n16) * 72;
    for (int ch = 0; ch < 32; ++ch) {
        int f0 = ch * 64;
        __syncthreads();   // prior chunk's consumers done
#pragma unroll
        for (int i = 0; i < 4; ++i) {
            glb_u16* g1 = (glb_u16*)(w1T + (size_t)(f0 + w1r[i]) * DD + w1b_log[i] * 8);
            lds_u16* l1 = (lds_u16*)(w1b + (16 * wave + 4 * i) * 128);
            __builtin_amdgcn_global_load_lds((const __attribute__((address_space(1))) unsigned*)g1,
                                             (__attribute__((address_space(3))) unsigned*)l1,
                                             16, 0, 0);
        }
#pragma unroll
        for (int i = 0; i < 4; ++i) {
            glb_u16* g2 = (glb_u16*)(w2T + (size_t)w2r[i] * FFDIM + f0 + w2b_log[i] * 8);
            lds_u16* l2 = (lds_u16*)(w2b + (32 * wave + 8 * i) * 64);
            __builtin_amdgcn_global_load_lds((const __attribute__((address_space(1))) unsigned*)g2,
                                             (__attribute__((address_space(3))) unsigned*)l2,
                                             16, 0, 0);
        }
        __syncthreads();   // drain: staged chunk visible
        // GEMM1: s = relu(h @ W1chunk + b1); each b-frag feeds both sub-tiles
#pragma unroll
        for (int t = 0; t < 4; ++t) {
            f32x4 a10 = (f32x4){0, 0, 0, 0};
            f32x4 a11 = (f32x4){0, 0, 0, 0};
#pragma unroll
            for (int ks = 0; ks < 4; ++ks) {
                bf16x8 b = *(const bf16x8*)(w1b + (t * 16 + n16) * 128 + (((ks * 4 + q) ^ swz) * 8));
                a10 = __builtin_amdgcn_mfma_f32_16x16x32_bf16(af[0][ks], b, a10, 0, 0, 0);
                a11 = __builtin_amdgcn_mfma_f32_16x16x32_bf16(af[1][ks], b, a11, 0, 0, 0);
            }
            float bb = bf2f(canon[512 + f0 + t * 16 + n16]);
#pragma unroll
            for (int reg = 0; reg < 4; ++reg) {
                float v0 = a10[reg] + bb;
                float v1 = a11[reg] + bb;
                v0 = v0 > 0.f ? v0 : 0.f;
                v1 = v1 > 0.f ? v1 : 0.f;
                srow_w0[reg * 72 + t * 16 + n16] = f2bf(v0);
                srow_w1[reg * 72 + t * 16 + n16] = f2bf(v1);
            }
        }
        asm volatile("" ::: "memory");
        // GEMM2: acc2 += s @ W2chunk (s rows wave-private; per-wave DS order ok)
#pragma unroll
        for (int ks2 = 0; ks2 < 2; ++ks2) {
            bf16x8 a20 = *(const bf16x8*)(srow_r0 + ks2 * 32 + q * 8);
            bf16x8 a21 = *(const bf16x8*)(srow_r1 + ks2 * 32 + q * 8);
#pragma unroll
            for (int t = 0; t < 8; ++t) {
                bf16x8 b = *(const bf16x8*)(w2b + (t * 16 + n16) * 64 + (((ks2 * 4 + q) ^ swz) * 8));
                acc2[0][t] = __builtin_amdgcn_mfma_f32_16x16x32_bf16(a20, b, acc2[0][t], 0, 0, 0);
                acc2[1][t] = __builtin_amdgcn_mfma_f32_16x16x32_bf16(a21, b, acc2[1][t], 0, 0, 0);
            }
        }
        asm volatile("" ::: "memory");
    }
    // epilogue: +b2 +residual, LN2 via 16-lane shuffles (row lives in one quad)
    float b2v[8], g2v[8], e2v[8];
#pragma unroll
    for (int t = 0; t < 8; ++t) {
        int col = t * 16 + n16;
        b2v[t] = bf2f(canon[2560 + col]);
        g2v[t] = bf2f(canon[2944 + col]);
        e2v[t] = bf2f(canon[3072 + col]);
    }
#pragma unroll
    for (int sub = 0; sub < 2; ++sub) {
#pragma unroll
        for (int reg = 0; reg < 4; ++reg) {
            int row = 32 * wave + 16 * sub + 4 * q + reg;
            int gm = m0 + row;
            bool ok = gm < TN;
            size_t gb = (size_t)(ok ? gm : 0) * DD;
            float v[8]; float s1 = 0.f, s2 = 0.f;
#pragma unroll
            for (int t = 0; t < 8; ++t) {
                float hres = bf2f(h1[gb + t * 16 + n16]);
                v[t] = acc2[sub][t][reg] + b2v[t] + hres;
                s1 += v[t]; s2 += v[t] * v[t];
            }
            s1 = segsum16(s1);
            s2 = segsum16(s2);
            float mu = s1 * (1.f / 128.f);
            float var = fmaxf(s2 * (1.f / 128.f) - mu * mu, 0.f);
            float rs = rsqrtf(var + 1e-5f);
            if (ok) {
#pragma unroll
                for (int t = 0; t < 8; ++t) {
                    float r = (v[t] - mu) * rs * g2v[t] + e2v[t];
                    if (f32) ((float*)outraw)[gb + t * 16 + n16] = r;
                    else     ((u16*)outraw)[gb + t * 16 + n16] = f2bf(r);
                }
            }
        }
    }
}

extern "C" void kernel_launch(void* const* d_in, const int* in_sizes, int n_in,
                              void* d_out, int out_size, void* d_ws, size_t ws_size,
                              hipStream_t stream) {
    const void* x    = d_in[0];
    const int* eidx  = (const int*)d_in[1];
    const void* Wl   = d_in[2];
    const void* bl   = d_in[3];
    const void* Wr   = d_in[4];
    const void* br   = d_in[5];
    const void* att  = d_in[6];
    const void* bgat = d_in[7];
    const void* W1   = d_in[8];
    const void* b1   = d_in[9];
    const void* W2   = d_in[10];
    const void* b2   = d_in[11];
    const void* g1   = d_in[12];
    const void* be1  = d_in[13];
    const void* g2   = d_in[14];
    const void* be2  = d_in[15];

    // ws layout (bytes): flag@0, rowoff@4096, colw@8192, canon@36864,
    // wlrT@65536, w1T@131072, w2T@655360, xl@1179648, xr/h1@22880256
    char* ws = (char*)d_ws;
    int* flag   = (int*)(ws);
    int* rowoff = (int*)(ws + 4096);
    int* colw   = (int*)(ws + 8192);
    u16* canon  = (u16*)(ws + 36864);
    u16* wlrT   = (u16*)(ws + 65536);
    u16* w1T    = (u16*)(ws + 131072);
    u16* w2T    = (u16*)(ws + 655360);
    u16* xl     = (u16*)(ws + 1179648);
    u16* xr     = (u16*)(ws + 22880256);
    u16* h1     = xr;   // k_gat reads xr[addr] before writing h1[addr]

    k_csr<<<1, 1024, 0, stream>>>(eidx, rowoff, colw);
    k_detect<<<1, 256, 0, stream>>>((const unsigned*)x, flag);
    k_prep<<<2189, 256, 0, stream>>>(Wl, Wr, W1, W2, bl, br, att, bgat, b1, b2,
                                     g1, be1, g2, be2, wlrT, w1T, w2T, canon, flag);
    k_linlr<<<(TN + 63) / 64, 256, 0, stream>>>(x, wlrT, canon, xl, xr, flag);
    k_gat<<<TN / 4, 256, 0, stream>>>(x, xl, xr, canon, rowoff, colw, h1, flag);
    k_ffn<<<(TN + 127) / 128, 256, 0, stream>>>(h1, w1T, w2T, canon, d_out, flag);
}